// Round 1
// baseline (406.841 us; speedup 1.0000x reference)
//
#include <hip/hip_runtime.h>
#include <stdint.h>

#define S_LEN 4096
#define NHEADS 16
#define DHEAD 64
#define EMB 1024
#define NBATCH 4
#define NBH (NBATCH * NHEADS)   // 64

typedef unsigned short u16t;
typedef __attribute__((ext_vector_type(8))) short short8;
typedef __attribute__((ext_vector_type(4))) float f32x4;

__device__ __forceinline__ u16t f2bf(float f) {
  unsigned int x = __float_as_uint(f);
  x += 0x7fffu + ((x >> 16) & 1u);
  return (u16t)(x >> 16);
}
__device__ __forceinline__ unsigned int pack2(float a, float b) {
  return (unsigned int)f2bf(a) | ((unsigned int)f2bf(b) << 16);
}
__device__ __forceinline__ float bflo(unsigned int v) { return __uint_as_float(v << 16); }
__device__ __forceinline__ float bfhi(unsigned int v) { return __uint_as_float(v & 0xffff0000u); }
__device__ __forceinline__ float fcomp(const float4& v, int k) {
  return k == 0 ? v.x : (k == 1 ? v.y : (k == 2 ? v.z : v.w));
}
__device__ __forceinline__ float phifn(float v) { return v > 0.f ? v + 1.f : __expf(v); }

// ---------------- K0: transpose+cast Wo (f32 [k][n]) -> WoT (bf16 [n][k]) ----
__global__ __launch_bounds__(256) void la_wot(const float* __restrict__ Wo,
                                              u16t* __restrict__ WoT) {
  __shared__ float t[64][65];
  int n0 = blockIdx.x * 64, k0 = blockIdx.y * 64;
  int tx = threadIdx.x, ty = threadIdx.y;  // 64 x 4
  for (int r = ty; r < 64; r += 4) t[r][tx] = Wo[(size_t)(k0 + r) * EMB + n0 + tx];
  __syncthreads();
  for (int r = ty; r < 64; r += 4)
    WoT[(size_t)(n0 + r) * EMB + k0 + tx] = f2bf(t[tx][r]);
}

// ---------------- K1a: phi_q = elu(x @ Wq[h]) + 1, stored bf16 --------------
__global__ __launch_bounds__(256) void la_phiq(const float* __restrict__ q,
                                               const float* __restrict__ Wq,
                                               u16t* __restrict__ phiq) {
  __shared__ float xs[128][68];
  __shared__ float w[64][64];
  int blk = blockIdx.x;
  int tile = blk & 31, bh = blk >> 5;
  int b = bh >> 4, h = bh & 15;
  int s0 = tile << 7;
  int t = threadIdx.x;
  {
    const float4* wsrc = (const float4*)(Wq + (size_t)h * 4096);
    float4* wdst = (float4*)(&w[0][0]);
#pragma unroll
    for (int i = 0; i < 4; ++i) wdst[t + 256 * i] = wsrc[t + 256 * i];
    const float* xb = q + ((size_t)b * S_LEN + s0) * EMB + h * 64;
#pragma unroll
    for (int i = 0; i < 8; ++i) {
      int idx = t + 256 * i;
      int r = idx >> 4, c4 = idx & 15;
      *(float4*)(&xs[r][c4 * 4]) = *(const float4*)(xb + (size_t)r * EMB + c4 * 4);
    }
  }
  __syncthreads();
  int tx = t & 7, ty = t >> 3;
  float acc[4][8];
#pragma unroll
  for (int i = 0; i < 4; ++i)
#pragma unroll
    for (int j = 0; j < 8; ++j) acc[i][j] = 0.f;
#pragma unroll 2
  for (int k0 = 0; k0 < 64; k0 += 4) {
    float4 xv[4];
#pragma unroll
    for (int i = 0; i < 4; ++i) xv[i] = *(const float4*)(&xs[ty * 4 + i][k0]);
#pragma unroll
    for (int kk = 0; kk < 4; ++kk) {
      float4 wa = *(const float4*)(&w[k0 + kk][tx * 8]);
      float4 wb = *(const float4*)(&w[k0 + kk][tx * 8 + 4]);
      float wv8[8] = {wa.x, wa.y, wa.z, wa.w, wb.x, wb.y, wb.z, wb.w};
#pragma unroll
      for (int i = 0; i < 4; ++i) {
        float xvi = fcomp(xv[i], kk);
#pragma unroll
        for (int j = 0; j < 8; ++j) acc[i][j] = fmaf(xvi, wv8[j], acc[i][j]);
      }
    }
  }
  u16t* pb = phiq + ((size_t)bh * S_LEN + s0 + ty * 4) * 64 + tx * 8;
#pragma unroll
  for (int i = 0; i < 4; ++i) {
    float p[8];
#pragma unroll
    for (int j = 0; j < 8; ++j) p[j] = phifn(acc[i][j]);
    uint4 o;
    o.x = pack2(p[0], p[1]); o.y = pack2(p[2], p[3]);
    o.z = pack2(p[4], p[5]); o.w = pack2(p[6], p[7]);
    *(uint4*)(pb + (size_t)i * 64) = o;
  }
}

// ---------------- K1b: phi_k, v -> per-tile kv partials + ksum partials -----
union SmemKV {
  struct { float xs[128][64]; float w[2][64][64]; } a;
  struct { float pk[128][64]; float vv[128][64]; } b;
};

__global__ __launch_bounds__(256) void la_kv(const float* __restrict__ q,
                                             const float* __restrict__ Wk,
                                             const float* __restrict__ Wv,
                                             float* __restrict__ kvpart,
                                             float* __restrict__ kspart) {
  __shared__ SmemKV sm;
  int blk = blockIdx.x;
  int tile = blk & 31, bh = blk >> 5;
  int b = bh >> 4, h = bh & 15;
  int s0 = tile << 7;
  int t = threadIdx.x;
  {
    const float4* s1 = (const float4*)(Wk + (size_t)h * 4096);
    const float4* s2 = (const float4*)(Wv + (size_t)h * 4096);
    float4* dw = (float4*)(&sm.a.w[0][0][0]);
#pragma unroll
    for (int i = 0; i < 4; ++i) dw[t + 256 * i] = s1[t + 256 * i];
#pragma unroll
    for (int i = 0; i < 4; ++i) dw[1024 + t + 256 * i] = s2[t + 256 * i];
    const float* xb = q + ((size_t)b * S_LEN + s0) * EMB + h * 64;
#pragma unroll
    for (int i = 0; i < 8; ++i) {
      int idx = t + 256 * i;
      int r = idx >> 4, c4 = idx & 15;
      *(float4*)(&sm.a.xs[r][c4 * 4]) = *(const float4*)(xb + (size_t)r * EMB + c4 * 4);
    }
  }
  __syncthreads();
  int tx = t & 7, ty = t >> 3;
  float accK[4][8], accV[4][8];
#pragma unroll
  for (int i = 0; i < 4; ++i)
#pragma unroll
    for (int j = 0; j < 8; ++j) { accK[i][j] = 0.f; accV[i][j] = 0.f; }
#pragma unroll 2
  for (int k0 = 0; k0 < 64; k0 += 4) {
    float4 xv[4];
#pragma unroll
    for (int i = 0; i < 4; ++i) xv[i] = *(const float4*)(&sm.a.xs[ty * 4 + i][k0]);
#pragma unroll
    for (int kk = 0; kk < 4; ++kk) {
      float4 ka_ = *(const float4*)(&sm.a.w[0][k0 + kk][tx * 8]);
      float4 kb_ = *(const float4*)(&sm.a.w[0][k0 + kk][tx * 8 + 4]);
      float4 va_ = *(const float4*)(&sm.a.w[1][k0 + kk][tx * 8]);
      float4 vb_ = *(const float4*)(&sm.a.w[1][k0 + kk][tx * 8 + 4]);
      float wk8[8] = {ka_.x, ka_.y, ka_.z, ka_.w, kb_.x, kb_.y, kb_.z, kb_.w};
      float wv8[8] = {va_.x, va_.y, va_.z, va_.w, vb_.x, vb_.y, vb_.z, vb_.w};
#pragma unroll
      for (int i = 0; i < 4; ++i) {
        float xvi = fcomp(xv[i], kk);
#pragma unroll
        for (int j = 0; j < 8; ++j) {
          accK[i][j] = fmaf(xvi, wk8[j], accK[i][j]);
          accV[i][j] = fmaf(xvi, wv8[j], accV[i][j]);
        }
      }
    }
  }
  __syncthreads();  // done reading sm.a; safe to overwrite via sm.b
#pragma unroll
  for (int i = 0; i < 4; ++i) {
    float4 pa = make_float4(phifn(accK[i][0]), phifn(accK[i][1]), phifn(accK[i][2]), phifn(accK[i][3]));
    float4 pb = make_float4(phifn(accK[i][4]), phifn(accK[i][5]), phifn(accK[i][6]), phifn(accK[i][7]));
    *(float4*)(&sm.b.pk[ty * 4 + i][tx * 8]) = pa;
    *(float4*)(&sm.b.pk[ty * 4 + i][tx * 8 + 4]) = pb;
    float4 va = make_float4(accV[i][0], accV[i][1], accV[i][2], accV[i][3]);
    float4 vb = make_float4(accV[i][4], accV[i][5], accV[i][6], accV[i][7]);
    *(float4*)(&sm.b.vv[ty * 4 + i][tx * 8]) = va;
    *(float4*)(&sm.b.vv[ty * 4 + i][tx * 8 + 4]) = vb;
  }
  __syncthreads();
  int tr = t >> 4, tc = t & 15;
  float ka[4][4];
#pragma unroll
  for (int i = 0; i < 4; ++i)
#pragma unroll
    for (int j = 0; j < 4; ++j) ka[i][j] = 0.f;
#pragma unroll 4
  for (int s = 0; s < 128; ++s) {
    float4 p4 = *(const float4*)(&sm.b.pk[s][tr * 4]);
    float4 v4 = *(const float4*)(&sm.b.vv[s][tc * 4]);
#pragma unroll
    for (int i = 0; i < 4; ++i) {
      float pi = fcomp(p4, i);
      ka[i][0] = fmaf(pi, v4.x, ka[i][0]);
      ka[i][1] = fmaf(pi, v4.y, ka[i][1]);
      ka[i][2] = fmaf(pi, v4.z, ka[i][2]);
      ka[i][3] = fmaf(pi, v4.w, ka[i][3]);
    }
  }
  float* kvp = kvpart + (size_t)blk * 4096;
#pragma unroll
  for (int i = 0; i < 4; ++i)
    *(float4*)(kvp + (tr * 4 + i) * 64 + tc * 4) = make_float4(ka[i][0], ka[i][1], ka[i][2], ka[i][3]);
  if (t < 64) {
    float a = 0.f;
#pragma unroll 8
    for (int s = 0; s < 128; ++s) a += sm.b.pk[s][t];
    kspart[(size_t)blk * 64 + t] = a;
  }
}

// ---------------- K2: reduce partials over the 32 S-tiles -------------------
__global__ __launch_bounds__(256) void la_reduce(const float* __restrict__ kvp,
                                                 const float* __restrict__ ksp,
                                                 float* __restrict__ kv,
                                                 float* __restrict__ ksum) {
  int bh = blockIdx.x, t = threadIdx.x;
#pragma unroll
  for (int i = 0; i < 16; ++i) {
    int idx = t + 256 * i;
    float a = 0.f;
    for (int p = 0; p < 32; ++p) a += kvp[((size_t)(bh * 32 + p)) * 4096 + idx];
    kv[(size_t)bh * 4096 + idx] = a;
  }
  if (t < 64) {
    float a = 0.f;
    for (int p = 0; p < 32; ++p) a += ksp[(size_t)(bh * 32 + p) * 64 + t];
    ksum[(size_t)bh * 64 + t] = a;
  }
}

// ---------------- K3: ctx = (phi_q @ kv) / (phi_q . ksum + eps) -> bf16 -----
__global__ __launch_bounds__(256) void la_ctx(const u16t* __restrict__ phiq,
                                              const float* __restrict__ kv,
                                              const float* __restrict__ ksum,
                                              u16t* __restrict__ comb) {
  __shared__ float pq[128][68];
  __shared__ float kvs[64][68];
  __shared__ float ksm[64];
  __shared__ float zz[128];
  int blk = blockIdx.x, tile = blk & 31, bh = blk >> 5;
  int b = bh >> 4, h = bh & 15;
  int s0 = tile << 7, t = threadIdx.x;
#pragma unroll
  for (int i = 0; i < 4; ++i) {
    int slot = t + (i << 8);
    int r = slot >> 4, c4 = slot & 15;
    *(float4*)(&kvs[r][c4 * 4]) = *(const float4*)(kv + (size_t)bh * 4096 + r * 64 + c4 * 4);
  }
  if (t < 64) ksm[t] = ksum[(size_t)bh * 64 + t];
  const u16t* pg = phiq + ((size_t)bh * S_LEN + s0) * 64;
#pragma unroll
  for (int i = 0; i < 4; ++i) {
    int slot = t + (i << 8);
    int r = slot >> 3, oc = slot & 7;
    uint4 u = *(const uint4*)(pg + (size_t)r * 64 + oc * 8);
    float4 fa = make_float4(bflo(u.x), bfhi(u.x), bflo(u.y), bfhi(u.y));
    float4 fb = make_float4(bflo(u.z), bfhi(u.z), bflo(u.w), bfhi(u.w));
    *(float4*)(&pq[r][oc * 8]) = fa;
    *(float4*)(&pq[r][oc * 8 + 4]) = fb;
  }
  __syncthreads();
  if (t < 128) {
    float a = 0.f;
#pragma unroll 8
    for (int k = 0; k < 64; ++k) a = fmaf(pq[t][k], ksm[k], a);
    zz[t] = a;
  }
  __syncthreads();
  int tx = t & 7, ty = t >> 3;
  float acc[4][8];
#pragma unroll
  for (int i = 0; i < 4; ++i)
#pragma unroll
    for (int j = 0; j < 8; ++j) acc[i][j] = 0.f;
#pragma unroll 2
  for (int k0 = 0; k0 < 64; k0 += 4) {
    float4 xv[4];
#pragma unroll
    for (int i = 0; i < 4; ++i) xv[i] = *(const float4*)(&pq[ty * 4 + i][k0]);
#pragma unroll
    for (int kk = 0; kk < 4; ++kk) {
      float4 wa = *(const float4*)(&kvs[k0 + kk][tx * 8]);
      float4 wb = *(const float4*)(&kvs[k0 + kk][tx * 8 + 4]);
      float wv8[8] = {wa.x, wa.y, wa.z, wa.w, wb.x, wb.y, wb.z, wb.w};
#pragma unroll
      for (int i = 0; i < 4; ++i) {
        float xvi = fcomp(xv[i], kk);
#pragma unroll
        for (int j = 0; j < 8; ++j) acc[i][j] = fmaf(xvi, wv8[j], acc[i][j]);
      }
    }
  }
#pragma unroll
  for (int i = 0; i < 4; ++i) {
    float inv = 1.f / (zz[ty * 4 + i] + 1e-6f);
    uint4 o;
    o.x = pack2(acc[i][0] * inv, acc[i][1] * inv);
    o.y = pack2(acc[i][2] * inv, acc[i][3] * inv);
    o.z = pack2(acc[i][4] * inv, acc[i][5] * inv);
    o.w = pack2(acc[i][6] * inv, acc[i][7] * inv);
    *(uint4*)(comb + ((size_t)b * S_LEN + s0 + ty * 4 + i) * EMB + h * 64 + tx * 8) = o;
  }
}

// ---------------- K4: out = combined(bf16) @ Wo  (MFMA, 128x128 tile) -------
__device__ __forceinline__ void stage_tile(const u16t* gbase, u16t* lds, int t) {
  // 128 rows x 64 cols bf16 tile; LDS linear rows of 128B; octet XOR-swizzle
  // applied via pre-swizzled global source (both-sides rule).
#pragma unroll
  for (int it = 0; it < 4; ++it) {
    int slot = it * 256 + t;
    int row = slot >> 3, oct = slot & 7;
    int octd = oct ^ (row & 7);
    const u16t* src = gbase + (size_t)row * 1024 + octd * 8;
    char* dst = (char*)lds + it * 4096 + ((t >> 6) << 10);
    __builtin_amdgcn_global_load_lds((const __attribute__((address_space(1))) unsigned int*)src,
                                     (__attribute__((address_space(3))) unsigned int*)dst,
                                     16, 0, 0);
  }
}

__global__ __launch_bounds__(256) void la_gemm(const u16t* __restrict__ A,
                                               const u16t* __restrict__ Bt,
                                               float* __restrict__ C) {
  __shared__ u16t Al[2][8192];
  __shared__ u16t Bl[2][8192];
  int t = threadIdx.x;
  int bid = blockIdx.x;
  int nt = bid & 7, mt = bid >> 3;
  const int M0 = mt * 128, N0 = nt * 128;
  int wave = t >> 6, lane = t & 63, l4 = lane >> 4, l16 = lane & 15;
  int wr = wave >> 1, wc = wave & 1;

  f32x4 acc[4][4];
#pragma unroll
  for (int m = 0; m < 4; ++m)
#pragma unroll
    for (int n = 0; n < 4; ++n) acc[m][n] = 0.f;

  stage_tile(A + (size_t)M0 * 1024, &Al[0][0], t);
  stage_tile(Bt + (size_t)N0 * 1024, &Bl[0][0], t);
  __syncthreads();

  for (int ks = 0; ks < 16; ++ks) {
    int cur = ks & 1;
    if (ks + 1 < 16) {
      stage_tile(A + (size_t)M0 * 1024 + (ks + 1) * 64, &Al[cur ^ 1][0], t);
      stage_tile(Bt + (size_t)N0 * 1024 + (ks + 1) * 64, &Bl[cur ^ 1][0], t);
    }
    short8 af[4][2], bf[4][2];
#pragma unroll
    for (int m = 0; m < 4; ++m) {
#pragma unroll
      for (int kk = 0; kk < 2; ++kk) {
        int oct = l4 + kk * 4;
        int row = wr * 64 + m * 16 + l16;
        af[m][kk] = *(const short8*)((const char*)&Al[cur][0] + row * 128 + ((oct ^ (row & 7)) << 4));
        int col = wc * 64 + m * 16 + l16;
        bf[m][kk] = *(const short8*)((const char*)&Bl[cur][0] + col * 128 + ((oct ^ (col & 7)) << 4));
      }
    }
#pragma unroll
    for (int m = 0; m < 4; ++m)
#pragma unroll
      for (int n = 0; n < 4; ++n) {
        acc[m][n] = __builtin_amdgcn_mfma_f32_16x16x32_bf16(af[m][0], bf[n][0], acc[m][n], 0, 0, 0);
        acc[m][n] = __builtin_amdgcn_mfma_f32_16x16x32_bf16(af[m][1], bf[n][1], acc[m][n], 0, 0, 0);
      }
    __syncthreads();
  }
#pragma unroll
  for (int m = 0; m < 4; ++m)
#pragma unroll
    for (int n = 0; n < 4; ++n)
#pragma unroll
      for (int j = 0; j < 4; ++j) {
        int row = M0 + wr * 64 + m * 16 + l4 * 4 + j;
        int col = N0 + wc * 64 + n * 16 + l16;
        C[(size_t)row * 1024 + col] = acc[m][n][j];
      }
}

// ---------------- launch ----------------------------------------------------
extern "C" void kernel_launch(void* const* d_in, const int* in_sizes, int n_in,
                              void* d_out, int out_size, void* d_ws, size_t ws_size,
                              hipStream_t stream) {
  const float* query = (const float*)d_in[0];
  const float* Wq = (const float*)d_in[1];
  const float* Wk = (const float*)d_in[2];
  const float* Wv = (const float*)d_in[3];
  const float* Wo = (const float*)d_in[4];
  float* out = (float*)d_out;
  char* ws = (char*)d_ws;

  // workspace carve (bytes)
  u16t* WoT    = (u16t*)(ws);                          // 2,097,152
  u16t* phiq   = (u16t*)(ws + 2097152);                // 33,554,432
  float* kvpart = (float*)(ws + 35651584);             // 33,554,432
  float* kspart = (float*)(ws + 69206016);             // 524,288
  float* kvbuf  = (float*)(ws + 69730304);             // 1,048,576
  float* ksbuf  = (float*)(ws + 70778880);             // 16,384
  u16t* comb   = (u16t*)(ws + 70795264);               // 33,554,432  -> total ~99.5 MB

  la_wot<<<dim3(16, 16), dim3(64, 4), 0, stream>>>(Wo, WoT);
  la_phiq<<<NBH * 32, 256, 0, stream>>>(query, Wq, phiq);
  la_kv<<<NBH * 32, 256, 0, stream>>>(query, Wk, Wv, kvpart, kspart);
  la_reduce<<<NBH, 256, 0, stream>>>(kvpart, kspart, kvbuf, ksbuf);
  la_ctx<<<NBH * 32, 256, 0, stream>>>(phiq, kvbuf, ksbuf, comb);
  la_gemm<<<1024, 256, 0, stream>>>(comb, WoT, out);
}

// Round 2
// 143.447 us; speedup vs baseline: 2.8362x; 2.8362x over previous
//
#include <hip/hip_runtime.h>
#include <stdint.h>

#define S_LEN 4096
#define NHEADS 16
#define DHEAD 64
#define EMB 1024
#define NBATCH 4
#define NBH (NBATCH * NHEADS)   // 64

typedef unsigned short u16t;
typedef __attribute__((ext_vector_type(8))) short short8;
typedef __attribute__((ext_vector_type(4))) float f32x4;

__device__ __forceinline__ u16t f2bf(float f) {
  unsigned int x = __float_as_uint(f);
  x += 0x7fffu + ((x >> 16) & 1u);
  return (u16t)(x >> 16);
}
__device__ __forceinline__ unsigned int pack2(float a, float b) {
  return (unsigned int)f2bf(a) | ((unsigned int)f2bf(b) << 16);
}
__device__ __forceinline__ float bf2f(u16t u) { return __uint_as_float(((unsigned int)u) << 16); }
__device__ __forceinline__ float phifn(float v) { return v > 0.f ? v + 1.f : __expf(v); }

// ---- stage 128x64 f32 tile (row stride EMB) -> bf16 LDS [128][72] ----------
__device__ __forceinline__ void stage_x_bf16(const float* __restrict__ xg,
                                             u16t* __restrict__ xs, int t) {
#pragma unroll
  for (int i = 0; i < 8; ++i) {
    int fi = i * 256 + t;
    int r = fi >> 4, c4 = fi & 15;
    float4 v = *(const float4*)(xg + (size_t)r * EMB + c4 * 4);
    uint2 p;
    p.x = pack2(v.x, v.y);
    p.y = pack2(v.z, v.w);
    *(uint2*)(&xs[r * 72 + c4 * 4]) = p;
  }
}

// ---- stage 8192B bf16 weight (pre-swizzled in global) via global_load_lds --
__device__ __forceinline__ void stage_w8k(const u16t* __restrict__ wg,
                                          u16t* __restrict__ lds, int t) {
#pragma unroll
  for (int c = 0; c < 2; ++c) {
    const u16t* src = wg + (size_t)(c * 256 + t) * 8;
    char* dst = (char*)lds + c * 4096 + ((t >> 6) << 10);
    __builtin_amdgcn_global_load_lds((const __attribute__((address_space(1))) unsigned int*)src,
                                     (__attribute__((address_space(3))) unsigned int*)dst,
                                     16, 0, 0);
  }
}

// ---------------- Kprep: W[h][d][e] f32 -> WT bf16 [h][e][oct^(e&7)][j] -----
__global__ __launch_bounds__(256) void la_prep(const float* __restrict__ Wq,
                                               const float* __restrict__ Wk,
                                               const float* __restrict__ Wv,
                                               u16t* __restrict__ WqT,
                                               u16t* __restrict__ WkT,
                                               u16t* __restrict__ WvT) {
  __shared__ float tmp[64][65];
  int blk = blockIdx.x;
  int mat = blk >> 4, h = blk & 15;
  const float* src = (mat == 0 ? Wq : (mat == 1 ? Wk : Wv)) + (size_t)h * 4096;
  u16t* dst = (mat == 0 ? WqT : (mat == 1 ? WkT : WvT)) + (size_t)h * 4096;
  int t = threadIdx.x;
#pragma unroll
  for (int p = 0; p < 16; ++p) {
    int i = p * 256 + t;
    tmp[i >> 6][i & 63] = src[i];
  }
  __syncthreads();
#pragma unroll
  for (int p = 0; p < 16; ++p) {
    int i = p * 256 + t;
    int e = i >> 6, r = i & 63, o = r >> 3, j = r & 7;
    dst[i] = f2bf(tmp[((o ^ (e & 7)) << 3) + j][e]);
  }
}

// ---------------- K0: transpose+cast Wo (f32 [k][n]) -> WoT (bf16 [n][k]) ----
__global__ __launch_bounds__(256) void la_wot(const float* __restrict__ Wo,
                                              u16t* __restrict__ WoT) {
  __shared__ float t[64][65];
  int n0 = blockIdx.x * 64, k0 = blockIdx.y * 64;
  int tx = threadIdx.x, ty = threadIdx.y;  // 64 x 4
  for (int r = ty; r < 64; r += 4) t[r][tx] = Wo[(size_t)(k0 + r) * EMB + n0 + tx];
  __syncthreads();
  for (int r = ty; r < 64; r += 4)
    WoT[(size_t)(n0 + r) * EMB + k0 + tx] = f2bf(t[tx][r]);
}

// ---------------- K_A: k,v proj (MFMA) -> phi -> kv partial (MFMA) ----------
__global__ __launch_bounds__(256) void la_kv2(const float* __restrict__ q,
                                              const u16t* __restrict__ WkT,
                                              const u16t* __restrict__ WvT,
                                              float* __restrict__ kvpart,
                                              float* __restrict__ kspart) {
  union Sm {
    struct { u16t xs[128 * 72]; u16t wk[4096]; u16t wv[4096]; } a;
    struct { u16t pkT[64 * 136]; u16t vT[64 * 136]; } b;
  };
  __shared__ Sm sm;
  int blk = blockIdx.x;
  int bh = blk >> 5, tile = blk & 31;
  int b = bh >> 4, h = bh & 15;
  int s0 = tile << 7;
  int t = threadIdx.x;
  int wave = t >> 6, lane = t & 63, l16 = lane & 15, g = lane >> 4;

  stage_x_bf16(q + ((size_t)b * S_LEN + s0) * EMB + h * 64, sm.a.xs, t);
  stage_w8k(WkT + (size_t)h * 4096, sm.a.wk, t);
  stage_w8k(WvT + (size_t)h * 4096, sm.a.wv, t);
  __syncthreads();

  f32x4 aK[2][4], aV[2][4];
#pragma unroll
  for (int m = 0; m < 2; ++m)
#pragma unroll
    for (int n = 0; n < 4; ++n) { aK[m][n] = 0.f; aV[m][n] = 0.f; }

  short8 af[2][2];
#pragma unroll
  for (int m = 0; m < 2; ++m)
#pragma unroll
    for (int kk = 0; kk < 2; ++kk)
      af[m][kk] = *(const short8*)(&sm.a.xs[(wave * 32 + m * 16 + l16) * 72 + kk * 32 + g * 8]);
#pragma unroll
  for (int n = 0; n < 4; ++n) {
    int e = n * 16 + l16;
#pragma unroll
    for (int kk = 0; kk < 2; ++kk) {
      int op = (kk * 4 + g) ^ (l16 & 7);
      short8 bK = *(const short8*)(&sm.a.wk[e * 64 + op * 8]);
      short8 bV = *(const short8*)(&sm.a.wv[e * 64 + op * 8]);
#pragma unroll
      for (int m = 0; m < 2; ++m) {
        aK[m][n] = __builtin_amdgcn_mfma_f32_16x16x32_bf16(af[m][kk], bK, aK[m][n], 0, 0, 0);
        aV[m][n] = __builtin_amdgcn_mfma_f32_16x16x32_bf16(af[m][kk], bV, aV[m][n], 0, 0, 0);
      }
    }
  }
  __syncthreads();  // all reads of sm.a done -> reuse as sm.b

#pragma unroll
  for (int m = 0; m < 2; ++m)
#pragma unroll
    for (int n = 0; n < 4; ++n) {
      int e = n * 16 + l16;
#pragma unroll
      for (int j = 0; j < 4; ++j) {
        int s = wave * 32 + m * 16 + g * 4 + j;
        sm.b.pkT[e * 136 + s] = f2bf(phifn(aK[m][n][j]));
        sm.b.vT[e * 136 + s] = f2bf(aV[m][n][j]);
      }
    }
  __syncthreads();

  // kv[d][e] partial over s=128: A = pk^T (rows d), B = v^T (rows e)
  f32x4 kacc[4];
#pragma unroll
  for (int n = 0; n < 4; ++n) kacc[n] = 0.f;
#pragma unroll
  for (int ks = 0; ks < 4; ++ks) {
    short8 pa = *(const short8*)(&sm.b.pkT[(wave * 16 + l16) * 136 + ks * 32 + g * 8]);
#pragma unroll
    for (int n = 0; n < 4; ++n) {
      short8 vb = *(const short8*)(&sm.b.vT[(n * 16 + l16) * 136 + ks * 32 + g * 8]);
      kacc[n] = __builtin_amdgcn_mfma_f32_16x16x32_bf16(pa, vb, kacc[n], 0, 0, 0);
    }
  }
  float* kp = kvpart + (size_t)blk * 4096;
#pragma unroll
  for (int n = 0; n < 4; ++n)
#pragma unroll
    for (int j = 0; j < 4; ++j)
      kp[(wave * 16 + g * 4 + j) * 64 + n * 16 + l16] = kacc[n][j];

  if (t < 64) {
    float a = 0.f;
#pragma unroll 8
    for (int s = 0; s < 128; ++s) a += bf2f(sm.b.pkT[t * 136 + s]);
    kspart[(size_t)blk * 64 + t] = a;
  }
}

// ---------------- K_B: reduce partials; emit kvT bf16 (pre-swizzled) + ksum -
__global__ __launch_bounds__(256) void la_red2(const float* __restrict__ kvpart,
                                               const float* __restrict__ kspart,
                                               u16t* __restrict__ kvT_g,
                                               float* __restrict__ ksum_g) {
  __shared__ float kvs[64][65];
  int bh = blockIdx.x, t = threadIdx.x;
  float acc[16];
#pragma unroll
  for (int p = 0; p < 16; ++p) acc[p] = 0.f;
  for (int part = 0; part < 32; ++part) {
    const float* base = kvpart + ((size_t)bh * 32 + part) * 4096;
#pragma unroll
    for (int p = 0; p < 16; ++p) acc[p] += base[p * 256 + t];
  }
#pragma unroll
  for (int p = 0; p < 16; ++p) {
    int i = p * 256 + t;
    kvs[i >> 6][i & 63] = acc[p];
  }
  if (t < 64) {
    float a = 0.f;
    for (int part = 0; part < 32; ++part) a += kspart[((size_t)bh * 32 + part) * 64 + t];
    ksum_g[(size_t)bh * 64 + t] = a;
  }
  __syncthreads();
#pragma unroll
  for (int p = 0; p < 16; ++p) {
    int i = p * 256 + t;
    int e = i >> 6, r = i & 63, o = r >> 3, j = r & 7;
    kvT_g[(size_t)bh * 4096 + i] = f2bf(kvs[((o ^ (e & 7)) << 3) + j][e]);
  }
}

// ---------------- K_C: q proj (MFMA) -> phi,z -> ctx (MFMA) -> comb bf16 ----
__global__ __launch_bounds__(256) void la_ctx2(const float* __restrict__ q,
                                               const u16t* __restrict__ WqT,
                                               const u16t* __restrict__ kvT_g,
                                               const float* __restrict__ ksum_g,
                                               u16t* __restrict__ comb) {
  __shared__ u16t xs[128 * 72];
  __shared__ u16t wq[4096];
  __shared__ u16t kvt[4096];
  __shared__ float ks[64];
  int blk = blockIdx.x;
  int bh = blk >> 5, tile = blk & 31;
  int b = bh >> 4, h = bh & 15;
  int s0 = tile << 7;
  int t = threadIdx.x;
  int wave = t >> 6, lane = t & 63, l16 = lane & 15, g = lane >> 4;

  stage_x_bf16(q + ((size_t)b * S_LEN + s0) * EMB + h * 64, xs, t);
  stage_w8k(WqT + (size_t)h * 4096, wq, t);
  stage_w8k(kvT_g + (size_t)bh * 4096, kvt, t);
  if (t < 64) ks[t] = ksum_g[(size_t)bh * 64 + t];
  __syncthreads();

  f32x4 aQ[2][4];
#pragma unroll
  for (int m = 0; m < 2; ++m)
#pragma unroll
    for (int n = 0; n < 4; ++n) aQ[m][n] = 0.f;
  short8 af[2][2];
#pragma unroll
  for (int m = 0; m < 2; ++m)
#pragma unroll
    for (int kk = 0; kk < 2; ++kk)
      af[m][kk] = *(const short8*)(&xs[(wave * 32 + m * 16 + l16) * 72 + kk * 32 + g * 8]);
#pragma unroll
  for (int n = 0; n < 4; ++n) {
    int e = n * 16 + l16;
#pragma unroll
    for (int kk = 0; kk < 2; ++kk) {
      int op = (kk * 4 + g) ^ (l16 & 7);
      short8 bQ = *(const short8*)(&wq[e * 64 + op * 8]);
#pragma unroll
      for (int m = 0; m < 2; ++m)
        aQ[m][n] = __builtin_amdgcn_mfma_f32_16x16x32_bf16(af[m][kk], bQ, aQ[m][n], 0, 0, 0);
    }
  }

  float ph[2][4][4];
#pragma unroll
  for (int m = 0; m < 2; ++m)
#pragma unroll
    for (int n = 0; n < 4; ++n)
#pragma unroll
      for (int j = 0; j < 4; ++j) ph[m][n][j] = phifn(aQ[m][n][j]);

  float z[2][4];
#pragma unroll
  for (int m = 0; m < 2; ++m)
#pragma unroll
    for (int j = 0; j < 4; ++j) {
      float zp = 0.f;
#pragma unroll
      for (int n = 0; n < 4; ++n) zp = fmaf(ph[m][n][j], ks[n * 16 + l16], zp);
      zp += __shfl_xor(zp, 1);
      zp += __shfl_xor(zp, 2);
      zp += __shfl_xor(zp, 4);
      zp += __shfl_xor(zp, 8);
      z[m][j] = zp;
    }
  __syncthreads();  // xs reads done -> reuse as phi_q store

#pragma unroll
  for (int m = 0; m < 2; ++m)
#pragma unroll
    for (int n = 0; n < 4; ++n)
#pragma unroll
      for (int j = 0; j < 4; ++j)
        xs[(wave * 32 + m * 16 + g * 4 + j) * 72 + n * 16 + l16] = f2bf(ph[m][n][j]);
  __syncthreads();

  f32x4 nacc[2][4];
#pragma unroll
  for (int m = 0; m < 2; ++m)
#pragma unroll
    for (int n = 0; n < 4; ++n) nacc[m][n] = 0.f;
#pragma unroll
  for (int kk = 0; kk < 2; ++kk) {
    short8 pa[2];
#pragma unroll
    for (int m = 0; m < 2; ++m)
      pa[m] = *(const short8*)(&xs[(wave * 32 + m * 16 + l16) * 72 + kk * 32 + g * 8]);
#pragma unroll
    for (int n = 0; n < 4; ++n) {
      int e = n * 16 + l16;
      int op = (kk * 4 + g) ^ (l16 & 7);
      short8 kb = *(const short8*)(&kvt[e * 64 + op * 8]);
#pragma unroll
      for (int m = 0; m < 2; ++m)
        nacc[m][n] = __builtin_amdgcn_mfma_f32_16x16x32_bf16(pa[m], kb, nacc[m][n], 0, 0, 0);
    }
  }
  __syncthreads();  // phi_q reads done -> reuse xs as ctx bounce

#pragma unroll
  for (int m = 0; m < 2; ++m)
#pragma unroll
    for (int j = 0; j < 4; ++j) {
      float inv = 1.f / (z[m][j] + 1e-6f);
      int s = wave * 32 + m * 16 + g * 4 + j;
#pragma unroll
      for (int n = 0; n < 4; ++n)
        xs[s * 72 + n * 16 + l16] = f2bf(nacc[m][n][j] * inv);
    }
  __syncthreads();

#pragma unroll
  for (int i = 0; i < 4; ++i) {
    int c = i * 256 + t;
    int r = c >> 3, qd = c & 7;
    uint4 v = *(const uint4*)(&xs[r * 72 + qd * 8]);
    *(uint4*)(&comb[((size_t)b * S_LEN + s0 + r) * EMB + h * 64 + qd * 8]) = v;
  }
}

// ---------------- K_D: out = comb(bf16) @ WoT  (MFMA, 128x128 tile) ---------
__device__ __forceinline__ void stage_tile(const u16t* gbase, u16t* lds, int t) {
#pragma unroll
  for (int it = 0; it < 4; ++it) {
    int slot = it * 256 + t;
    int row = slot >> 3, oct = slot & 7;
    int octd = oct ^ (row & 7);
    const u16t* src = gbase + (size_t)row * 1024 + octd * 8;
    char* dst = (char*)lds + it * 4096 + ((t >> 6) << 10);
    __builtin_amdgcn_global_load_lds((const __attribute__((address_space(1))) unsigned int*)src,
                                     (__attribute__((address_space(3))) unsigned int*)dst,
                                     16, 0, 0);
  }
}

__global__ __launch_bounds__(256) void la_gemm(const u16t* __restrict__ A,
                                               const u16t* __restrict__ Bt,
                                               float* __restrict__ C) {
  __shared__ u16t Al[2][8192];
  __shared__ u16t Bl[2][8192];
  int t = threadIdx.x;
  int bid = blockIdx.x;
  int nt = bid & 7, mt = bid >> 3;
  const int M0 = mt * 128, N0 = nt * 128;
  int wave = t >> 6, lane = t & 63, l4 = lane >> 4, l16 = lane & 15;
  int wr = wave >> 1, wc = wave & 1;

  f32x4 acc[4][4];
#pragma unroll
  for (int m = 0; m < 4; ++m)
#pragma unroll
    for (int n = 0; n < 4; ++n) acc[m][n] = 0.f;

  stage_tile(A + (size_t)M0 * 1024, &Al[0][0], t);
  stage_tile(Bt + (size_t)N0 * 1024, &Bl[0][0], t);
  __syncthreads();

  for (int ks = 0; ks < 16; ++ks) {
    int cur = ks & 1;
    if (ks + 1 < 16) {
      stage_tile(A + (size_t)M0 * 1024 + (ks + 1) * 64, &Al[cur ^ 1][0], t);
      stage_tile(Bt + (size_t)N0 * 1024 + (ks + 1) * 64, &Bl[cur ^ 1][0], t);
    }
    short8 af[4][2], bf[4][2];
#pragma unroll
    for (int m = 0; m < 4; ++m) {
#pragma unroll
      for (int kk = 0; kk < 2; ++kk) {
        int oct = l4 + kk * 4;
        int row = wr * 64 + m * 16 + l16;
        af[m][kk] = *(const short8*)((const char*)&Al[cur][0] + row * 128 + ((oct ^ (row & 7)) << 4));
        int col = wc * 64 + m * 16 + l16;
        bf[m][kk] = *(const short8*)((const char*)&Bl[cur][0] + col * 128 + ((oct ^ (col & 7)) << 4));
      }
    }
#pragma unroll
    for (int m = 0; m < 4; ++m)
#pragma unroll
      for (int n = 0; n < 4; ++n) {
        acc[m][n] = __builtin_amdgcn_mfma_f32_16x16x32_bf16(af[m][0], bf[n][0], acc[m][n], 0, 0, 0);
        acc[m][n] = __builtin_amdgcn_mfma_f32_16x16x32_bf16(af[m][1], bf[n][1], acc[m][n], 0, 0, 0);
      }
    __syncthreads();
  }
#pragma unroll
  for (int m = 0; m < 4; ++m)
#pragma unroll
    for (int n = 0; n < 4; ++n)
#pragma unroll
      for (int j = 0; j < 4; ++j) {
        int row = M0 + wr * 64 + m * 16 + l4 * 4 + j;
        int col = N0 + wc * 64 + n * 16 + l16;
        C[(size_t)row * 1024 + col] = acc[m][n][j];
      }
}

// ---------------- launch ----------------------------------------------------
extern "C" void kernel_launch(void* const* d_in, const int* in_sizes, int n_in,
                              void* d_out, int out_size, void* d_ws, size_t ws_size,
                              hipStream_t stream) {
  const float* query = (const float*)d_in[0];
  const float* Wq = (const float*)d_in[1];
  const float* Wk = (const float*)d_in[2];
  const float* Wv = (const float*)d_in[3];
  const float* Wo = (const float*)d_in[4];
  float* out = (float*)d_out;
  char* ws = (char*)d_ws;

  // workspace carve (bytes)
  u16t* WoT     = (u16t*)(ws);                 //  2,097,152
  u16t* WqT     = (u16t*)(ws + 2097152);       //    131,072
  u16t* WkT     = (u16t*)(ws + 2228224);       //    131,072
  u16t* WvT     = (u16t*)(ws + 2359296);       //    131,072
  float* kvpart = (float*)(ws + 2490368);      // 33,554,432
  float* kspart = (float*)(ws + 36044800);     //    524,288
  u16t* kvT_g   = (u16t*)(ws + 36569088);      //    524,288
  float* ksum_g = (float*)(ws + 37093376);     //     16,384
  u16t* comb    = (u16t*)(ws + 37109760);      // 33,554,432  -> total ~70.7 MB

  la_prep<<<48, 256, 0, stream>>>(Wq, Wk, Wv, WqT, WkT, WvT);
  la_wot<<<dim3(16, 16), dim3(64, 4), 0, stream>>>(Wo, WoT);
  la_kv2<<<NBH * 32, 256, 0, stream>>>(query, WkT, WvT, kvpart, kspart);
  la_red2<<<NBH, 256, 0, stream>>>(kvpart, kspart, kvT_g, ksum_g);
  la_ctx2<<<NBH * 32, 256, 0, stream>>>(query, WqT, kvT_g, ksum_g, comb);
  la_gemm<<<1024, 256, 0, stream>>>(comb, WoT, out);
}

// Round 3
// 122.674 us; speedup vs baseline: 3.3164x; 1.1693x over previous
//
#include <hip/hip_runtime.h>
#include <stdint.h>

#define S_LEN 4096
#define NHEADS 16
#define DHEAD 64
#define EMB 1024
#define NBATCH 4
#define NBH (NBATCH * NHEADS)   // 64

typedef unsigned short u16t;
typedef __attribute__((ext_vector_type(8))) short short8;
typedef __attribute__((ext_vector_type(4))) float f32x4;

__device__ __forceinline__ u16t f2bf(float f) {
  unsigned int x = __float_as_uint(f);
  x += 0x7fffu + ((x >> 16) & 1u);
  return (u16t)(x >> 16);
}
__device__ __forceinline__ unsigned int pack2(float a, float b) {
  return (unsigned int)f2bf(a) | ((unsigned int)f2bf(b) << 16);
}
__device__ __forceinline__ float bf2f(u16t u) { return __uint_as_float(((unsigned int)u) << 16); }
__device__ __forceinline__ float phifn(float v) { return v > 0.f ? v + 1.f : __expf(v); }

// ---- stage 128x64 f32 tile (row stride EMB) -> bf16 LDS [128][72] ----------
__device__ __forceinline__ void stage_x_bf16(const float* __restrict__ xg,
                                             u16t* __restrict__ xs, int t) {
#pragma unroll
  for (int i = 0; i < 8; ++i) {
    int fi = i * 256 + t;
    int r = fi >> 4, c4 = fi & 15;
    float4 v = *(const float4*)(xg + (size_t)r * EMB + c4 * 4);
    uint2 p;
    p.x = pack2(v.x, v.y);
    p.y = pack2(v.z, v.w);
    *(uint2*)(&xs[r * 72 + c4 * 4]) = p;
  }
}

// ---- stage 8192B bf16 weight (pre-swizzled in global) via global_load_lds --
__device__ __forceinline__ void stage_w8k(const u16t* __restrict__ wg,
                                          u16t* __restrict__ lds, int t) {
#pragma unroll
  for (int c = 0; c < 2; ++c) {
    const u16t* src = wg + (size_t)(c * 256 + t) * 8;
    char* dst = (char*)lds + c * 4096 + ((t >> 6) << 10);
    __builtin_amdgcn_global_load_lds((const __attribute__((address_space(1))) unsigned int*)src,
                                     (__attribute__((address_space(3))) unsigned int*)dst,
                                     16, 0, 0);
  }
}

// ---------------- Kprep: W[h][d][e] f32 -> WT bf16 [h][e][oct^(e&7)][j] -----
__global__ __launch_bounds__(256) void la_prep(const float* __restrict__ Wq,
                                               const float* __restrict__ Wk,
                                               const float* __restrict__ Wv,
                                               u16t* __restrict__ WqT,
                                               u16t* __restrict__ WkT,
                                               u16t* __restrict__ WvT) {
  __shared__ float tmp[64][65];
  int blk = blockIdx.x;
  int mat = blk >> 4, h = blk & 15;
  const float* src = (mat == 0 ? Wq : (mat == 1 ? Wk : Wv)) + (size_t)h * 4096;
  u16t* dst = (mat == 0 ? WqT : (mat == 1 ? WkT : WvT)) + (size_t)h * 4096;
  int t = threadIdx.x;
#pragma unroll
  for (int p = 0; p < 16; ++p) {
    int i = p * 256 + t;
    tmp[i >> 6][i & 63] = src[i];
  }
  __syncthreads();
#pragma unroll
  for (int p = 0; p < 16; ++p) {
    int i = p * 256 + t;
    int e = i >> 6, r = i & 63, o = r >> 3, j = r & 7;
    dst[i] = f2bf(tmp[((o ^ (e & 7)) << 3) + j][e]);
  }
}

// ---------------- K0: transpose+cast Wo (f32 [k][n]) -> WoT (bf16 [n][k]) ----
__global__ __launch_bounds__(256) void la_wot(const float* __restrict__ Wo,
                                              u16t* __restrict__ WoT) {
  __shared__ float t[64][65];
  int n0 = blockIdx.x * 64, k0 = blockIdx.y * 64;
  int tx = threadIdx.x, ty = threadIdx.y;  // 64 x 4
  for (int r = ty; r < 64; r += 4) t[r][tx] = Wo[(size_t)(k0 + r) * EMB + n0 + tx];
  __syncthreads();
  for (int r = ty; r < 64; r += 4)
    WoT[(size_t)(n0 + r) * EMB + k0 + tx] = f2bf(t[tx][r]);
}

// ---------------- K_A: k,v proj (MFMA) -> phi -> kv partial (MFMA) ----------
__global__ __launch_bounds__(256) void la_kv2(const float* __restrict__ q,
                                              const u16t* __restrict__ WkT,
                                              const u16t* __restrict__ WvT,
                                              float* __restrict__ kvpart,
                                              float* __restrict__ kspart) {
  union Sm {
    struct { u16t xs[128 * 72]; u16t wk[4096]; u16t wv[4096]; } a;
    struct { u16t pkT[64 * 136]; u16t vT[64 * 136]; } b;
  };
  __shared__ Sm sm;
  int blk = blockIdx.x;
  int bh = blk >> 5, tile = blk & 31;
  int b = bh >> 4, h = bh & 15;
  int s0 = tile << 7;
  int t = threadIdx.x;
  int wave = t >> 6, lane = t & 63, l16 = lane & 15, g = lane >> 4;

  stage_x_bf16(q + ((size_t)b * S_LEN + s0) * EMB + h * 64, sm.a.xs, t);
  stage_w8k(WkT + (size_t)h * 4096, sm.a.wk, t);
  stage_w8k(WvT + (size_t)h * 4096, sm.a.wv, t);
  __syncthreads();

  f32x4 aK[2][4], aV[2][4];
#pragma unroll
  for (int m = 0; m < 2; ++m)
#pragma unroll
    for (int n = 0; n < 4; ++n) { aK[m][n] = 0.f; aV[m][n] = 0.f; }

  short8 af[2][2];
#pragma unroll
  for (int m = 0; m < 2; ++m)
#pragma unroll
    for (int kk = 0; kk < 2; ++kk)
      af[m][kk] = *(const short8*)(&sm.a.xs[(wave * 32 + m * 16 + l16) * 72 + kk * 32 + g * 8]);
#pragma unroll
  for (int n = 0; n < 4; ++n) {
    int e = n * 16 + l16;
#pragma unroll
    for (int kk = 0; kk < 2; ++kk) {
      int op = (kk * 4 + g) ^ (l16 & 7);
      short8 bK = *(const short8*)(&sm.a.wk[e * 64 + op * 8]);
      short8 bV = *(const short8*)(&sm.a.wv[e * 64 + op * 8]);
#pragma unroll
      for (int m = 0; m < 2; ++m) {
        aK[m][n] = __builtin_amdgcn_mfma_f32_16x16x32_bf16(af[m][kk], bK, aK[m][n], 0, 0, 0);
        aV[m][n] = __builtin_amdgcn_mfma_f32_16x16x32_bf16(af[m][kk], bV, aV[m][n], 0, 0, 0);
      }
    }
  }
  __syncthreads();  // all reads of sm.a done -> reuse as sm.b

#pragma unroll
  for (int m = 0; m < 2; ++m)
#pragma unroll
    for (int n = 0; n < 4; ++n) {
      int e = n * 16 + l16;
#pragma unroll
      for (int j = 0; j < 4; ++j) {
        int s = wave * 32 + m * 16 + g * 4 + j;
        sm.b.pkT[e * 136 + s] = f2bf(phifn(aK[m][n][j]));
        sm.b.vT[e * 136 + s] = f2bf(aV[m][n][j]);
      }
    }
  __syncthreads();

  // kv[d][e] partial over s=128: A = pk^T (rows d), B = v^T (rows e)
  f32x4 kacc[4];
#pragma unroll
  for (int n = 0; n < 4; ++n) kacc[n] = 0.f;
#pragma unroll
  for (int ks = 0; ks < 4; ++ks) {
    short8 pa = *(const short8*)(&sm.b.pkT[(wave * 16 + l16) * 136 + ks * 32 + g * 8]);
#pragma unroll
    for (int n = 0; n < 4; ++n) {
      short8 vb = *(const short8*)(&sm.b.vT[(n * 16 + l16) * 136 + ks * 32 + g * 8]);
      kacc[n] = __builtin_amdgcn_mfma_f32_16x16x32_bf16(pa, vb, kacc[n], 0, 0, 0);
    }
  }
  float* kp = kvpart + (size_t)blk * 4096;
#pragma unroll
  for (int n = 0; n < 4; ++n)
#pragma unroll
    for (int j = 0; j < 4; ++j)
      kp[(wave * 16 + g * 4 + j) * 64 + n * 16 + l16] = kacc[n][j];

  if (t < 64) {
    float a = 0.f;
#pragma unroll 8
    for (int s = 0; s < 128; ++s) a += bf2f(sm.b.pkT[t * 136 + s]);
    kspart[(size_t)blk * 64 + t] = a;
  }
}

// ---------------- K_B: reduce partials; emit kvT bf16 (pre-swizzled) + ksum -
__global__ __launch_bounds__(256) void la_red2(const float* __restrict__ kvpart,
                                               const float* __restrict__ kspart,
                                               u16t* __restrict__ kvT_g,
                                               float* __restrict__ ksum_g) {
  __shared__ float kvs[64][65];
  int bh = blockIdx.x, t = threadIdx.x;
  float acc[16];
#pragma unroll
  for (int p = 0; p < 16; ++p) acc[p] = 0.f;
  for (int part = 0; part < 32; ++part) {
    const float* base = kvpart + ((size_t)bh * 32 + part) * 4096;
#pragma unroll
    for (int p = 0; p < 16; ++p) acc[p] += base[p * 256 + t];
  }
#pragma unroll
  for (int p = 0; p < 16; ++p) {
    int i = p * 256 + t;
    kvs[i >> 6][i & 63] = acc[p];
  }
  if (t < 64) {
    float a = 0.f;
    for (int part = 0; part < 32; ++part) a += kspart[((size_t)bh * 32 + part) * 64 + t];
    ksum_g[(size_t)bh * 64 + t] = a;
  }
  __syncthreads();
#pragma unroll
  for (int p = 0; p < 16; ++p) {
    int i = p * 256 + t;
    int e = i >> 6, r = i & 63, o = r >> 3, j = r & 7;
    kvT_g[(size_t)bh * 4096 + i] = f2bf(kvs[((o ^ (e & 7)) << 3) + j][e]);
  }
}

// ---------------- K_C: q proj (MFMA) -> phi,z -> ctx (MFMA) -> comb bf16 ----
__global__ __launch_bounds__(256) void la_ctx2(const float* __restrict__ q,
                                               const u16t* __restrict__ WqT,
                                               const u16t* __restrict__ kvT_g,
                                               const float* __restrict__ ksum_g,
                                               u16t* __restrict__ comb) {
  __shared__ u16t xs[128 * 72];
  __shared__ u16t wq[4096];
  __shared__ u16t kvt[4096];
  __shared__ float ks[64];
  int blk = blockIdx.x;
  int bh = blk >> 5, tile = blk & 31;
  int b = bh >> 4, h = bh & 15;
  int s0 = tile << 7;
  int t = threadIdx.x;
  int wave = t >> 6, lane = t & 63, l16 = lane & 15, g = lane >> 4;

  stage_x_bf16(q + ((size_t)b * S_LEN + s0) * EMB + h * 64, xs, t);
  stage_w8k(WqT + (size_t)h * 4096, wq, t);
  stage_w8k(kvT_g + (size_t)bh * 4096, kvt, t);
  if (t < 64) ks[t] = ksum_g[(size_t)bh * 64 + t];
  __syncthreads();

  f32x4 aQ[2][4];
#pragma unroll
  for (int m = 0; m < 2; ++m)
#pragma unroll
    for (int n = 0; n < 4; ++n) aQ[m][n] = 0.f;
  short8 af[2][2];
#pragma unroll
  for (int m = 0; m < 2; ++m)
#pragma unroll
    for (int kk = 0; kk < 2; ++kk)
      af[m][kk] = *(const short8*)(&xs[(wave * 32 + m * 16 + l16) * 72 + kk * 32 + g * 8]);
#pragma unroll
  for (int n = 0; n < 4; ++n) {
    int e = n * 16 + l16;
#pragma unroll
    for (int kk = 0; kk < 2; ++kk) {
      int op = (kk * 4 + g) ^ (l16 & 7);
      short8 bQ = *(const short8*)(&wq[e * 64 + op * 8]);
#pragma unroll
      for (int m = 0; m < 2; ++m)
        aQ[m][n] = __builtin_amdgcn_mfma_f32_16x16x32_bf16(af[m][kk], bQ, aQ[m][n], 0, 0, 0);
    }
  }

  float ph[2][4][4];
#pragma unroll
  for (int m = 0; m < 2; ++m)
#pragma unroll
    for (int n = 0; n < 4; ++n)
#pragma unroll
      for (int j = 0; j < 4; ++j) ph[m][n][j] = phifn(aQ[m][n][j]);

  float z[2][4];
#pragma unroll
  for (int m = 0; m < 2; ++m)
#pragma unroll
    for (int j = 0; j < 4; ++j) {
      float zp = 0.f;
#pragma unroll
      for (int n = 0; n < 4; ++n) zp = fmaf(ph[m][n][j], ks[n * 16 + l16], zp);
      zp += __shfl_xor(zp, 1);
      zp += __shfl_xor(zp, 2);
      zp += __shfl_xor(zp, 4);
      zp += __shfl_xor(zp, 8);
      z[m][j] = zp;
    }
  __syncthreads();  // xs reads done -> reuse as phi_q store

#pragma unroll
  for (int m = 0; m < 2; ++m)
#pragma unroll
    for (int n = 0; n < 4; ++n)
#pragma unroll
      for (int j = 0; j < 4; ++j)
        xs[(wave * 32 + m * 16 + g * 4 + j) * 72 + n * 16 + l16] = f2bf(ph[m][n][j]);
  __syncthreads();

  f32x4 nacc[2][4];
#pragma unroll
  for (int m = 0; m < 2; ++m)
#pragma unroll
    for (int n = 0; n < 4; ++n) nacc[m][n] = 0.f;
#pragma unroll
  for (int kk = 0; kk < 2; ++kk) {
    short8 pa[2];
#pragma unroll
    for (int m = 0; m < 2; ++m)
      pa[m] = *(const short8*)(&xs[(wave * 32 + m * 16 + l16) * 72 + kk * 32 + g * 8]);
#pragma unroll
    for (int n = 0; n < 4; ++n) {
      int e = n * 16 + l16;
      int op = (kk * 4 + g) ^ (l16 & 7);
      short8 kb = *(const short8*)(&kvt[e * 64 + op * 8]);
#pragma unroll
      for (int m = 0; m < 2; ++m)
        nacc[m][n] = __builtin_amdgcn_mfma_f32_16x16x32_bf16(pa[m], kb, nacc[m][n], 0, 0, 0);
    }
  }
  __syncthreads();  // phi_q reads done -> reuse xs as ctx bounce

#pragma unroll
  for (int m = 0; m < 2; ++m)
#pragma unroll
    for (int j = 0; j < 4; ++j) {
      float inv = 1.f / (z[m][j] + 1e-6f);
      int s = wave * 32 + m * 16 + g * 4 + j;
#pragma unroll
      for (int n = 0; n < 4; ++n)
        xs[s * 72 + n * 16 + l16] = f2bf(nacc[m][n][j] * inv);
    }
  __syncthreads();

#pragma unroll
  for (int i = 0; i < 4; ++i) {
    int c = i * 256 + t;
    int r = c >> 3, qd = c & 7;
    uint4 v = *(const uint4*)(&xs[r * 72 + qd * 8]);
    *(uint4*)(&comb[((size_t)b * S_LEN + s0 + r) * EMB + h * 64 + qd * 8]) = v;
  }
}

// ---------------- K_D: out = comb(bf16) @ WoT  (MFMA, 256x256 8-phase) ------
// half-tile stage: 128 rows x 64 cols bf16 into [256][64] LDS buffer.
// LDS linear (gload_lds), source address octet-XOR swizzled (both-sides rule).
__device__ __forceinline__ void stage_half(const u16t* __restrict__ gbase,
                                           u16t* __restrict__ lbuf,
                                           int half, int t) {
#pragma unroll
  for (int it = 0; it < 2; ++it) {
    int slot = it * 512 + t;                 // 0..1023
    int row = half * 128 + (slot >> 3);      // tile row
    int oct = slot & 7;
    const u16t* src = gbase + (size_t)row * EMB + (((oct ^ (row & 7)) << 3));
    char* dst = (char*)lbuf + ((half * 128 + it * 64 + ((t >> 6) << 3)) << 7);
    __builtin_amdgcn_global_load_lds((const __attribute__((address_space(1))) unsigned int*)src,
                                     (__attribute__((address_space(3))) unsigned int*)dst,
                                     16, 0, 0);
  }
}

#define GFENCE asm volatile("" ::: "memory")

// one phase: quadrant (QM,QN). 12 ds_read_b128 + stage + wait + bar + 16 MFMA + bar
#define PHASE(QM, QN, STAGE_STMT, WAIT_STMT)                                              \
  do {                                                                                    \
    short8 paf[4][2], pbf[2][2];                                                          \
    _Pragma("unroll") for (int mi = 0; mi < 4; ++mi) _Pragma("unroll")                    \
        for (int kk = 0; kk < 2; ++kk) {                                                  \
      int rr = (QM) * 128 + wr2 * 64 + mi * 16 + l16;                                     \
      paf[mi][kk] = *(const short8*)((const char*)Acur + rr * 128 +                       \
                                     ((((kk << 2) | g) ^ (rr & 7)) << 4));                \
    }                                                                                     \
    _Pragma("unroll") for (int ni = 0; ni < 2; ++ni) _Pragma("unroll")                    \
        for (int kk = 0; kk < 2; ++kk) {                                                  \
      int rr = (QN) * 128 + wc2 * 32 + ni * 16 + l16;                                     \
      pbf[ni][kk] = *(const short8*)((const char*)Bcur + rr * 128 +                       \
                                     ((((kk << 2) | g) ^ (rr & 7)) << 4));                \
    }                                                                                     \
    STAGE_STMT;                                                                           \
    WAIT_STMT;                                                                            \
    __builtin_amdgcn_s_barrier();                                                         \
    GFENCE;                                                                               \
    __builtin_amdgcn_s_setprio(1);                                                        \
    _Pragma("unroll") for (int mi = 0; mi < 4; ++mi) _Pragma("unroll")                    \
        for (int ni = 0; ni < 2; ++ni) {                                                  \
      acc[QM][QN][mi][ni] = __builtin_amdgcn_mfma_f32_16x16x32_bf16(                      \
          paf[mi][0], pbf[ni][0], acc[QM][QN][mi][ni], 0, 0, 0);                          \
      acc[QM][QN][mi][ni] = __builtin_amdgcn_mfma_f32_16x16x32_bf16(                      \
          paf[mi][1], pbf[ni][1], acc[QM][QN][mi][ni], 0, 0, 0);                          \
    }                                                                                     \
    __builtin_amdgcn_s_setprio(0);                                                        \
    GFENCE;                                                                               \
    __builtin_amdgcn_s_barrier();                                                         \
    GFENCE;                                                                               \
  } while (0)

__global__ __launch_bounds__(512, 2) void la_gemm8(const u16t* __restrict__ A,
                                                   const u16t* __restrict__ Bt,
                                                   float* __restrict__ C) {
  __shared__ u16t Al[2][16384];  // [buf][256 rows][64 cols]
  __shared__ u16t Bl[2][16384];
  int t = threadIdx.x;
  int bid = blockIdx.x;
  int swz = ((bid & 7) << 5) + (bid >> 3);  // XCD swizzle, 256 blocks % 8 == 0
  int mt = swz >> 2, nt = swz & 3;
  const int M0 = mt * 256, N0 = nt * 256;
  int wave = t >> 6, lane = t & 63;
  int l16 = lane & 15, g = lane >> 4;
  int wr2 = wave >> 2, wc2 = wave & 3;  // wave tile: rows wr2*64(+qm*128), cols wc2*32(+qn*128)

  f32x4 acc[2][2][4][2];
#pragma unroll
  for (int qm = 0; qm < 2; ++qm)
#pragma unroll
    for (int qn = 0; qn < 2; ++qn)
#pragma unroll
      for (int mi = 0; mi < 4; ++mi)
#pragma unroll
        for (int ni = 0; ni < 2; ++ni) acc[qm][qn][mi][ni] = 0.f;

  const u16t* Asrc = A + (size_t)M0 * EMB;
  const u16t* Bsrc = Bt + (size_t)N0 * EMB;

  // prologue: tile 0 -> buf 0 (need-order), keep Bh1/Ah1 in flight
  stage_half(Asrc, Al[0], 0, t);
  stage_half(Bsrc, Bl[0], 0, t);
  stage_half(Bsrc, Bl[0], 1, t);
  stage_half(Asrc, Al[0], 1, t);
  asm volatile("s_waitcnt vmcnt(4)" ::: "memory");
  __builtin_amdgcn_s_barrier();
  GFENCE;

  for (int kt = 0; kt < 15; ++kt) {
    const u16t* Acur = Al[kt & 1];
    const u16t* Bcur = Bl[kt & 1];
    u16t* Anxt = Al[(kt + 1) & 1];
    u16t* Bnxt = Bl[(kt + 1) & 1];
    const u16t* An = Asrc + (kt + 1) * 64;
    const u16t* Bn = Bsrc + (kt + 1) * 64;
    PHASE(0, 0, { stage_half(An, Anxt, 0, t); stage_half(Bn, Bnxt, 0, t); },
          asm volatile("s_waitcnt vmcnt(6)" ::: "memory"));
    PHASE(0, 1, { stage_half(Bn, Bnxt, 1, t); },
          asm volatile("s_waitcnt vmcnt(6)" ::: "memory"));
    PHASE(1, 0, { stage_half(An, Anxt, 1, t); }, GFENCE);
    PHASE(1, 1, {}, asm volatile("s_waitcnt vmcnt(4)" ::: "memory"));
  }
  {  // peeled last tile (kt = 15): no staging, tighter drains
    const u16t* Acur = Al[1];
    const u16t* Bcur = Bl[1];
    PHASE(0, 0, {}, asm volatile("s_waitcnt vmcnt(2)" ::: "memory"));
    PHASE(0, 1, {}, asm volatile("s_waitcnt vmcnt(0)" ::: "memory"));
    PHASE(1, 0, {}, GFENCE);
    PHASE(1, 1, {}, GFENCE);
  }

#pragma unroll
  for (int qm = 0; qm < 2; ++qm)
#pragma unroll
    for (int qn = 0; qn < 2; ++qn)
#pragma unroll
      for (int mi = 0; mi < 4; ++mi)
#pragma unroll
        for (int ni = 0; ni < 2; ++ni)
#pragma unroll
          for (int j = 0; j < 4; ++j) {
            int row = M0 + qm * 128 + wr2 * 64 + mi * 16 + g * 4 + j;
            int col = N0 + qn * 128 + wc2 * 32 + ni * 16 + l16;
            C[(size_t)row * EMB + col] = acc[qm][qn][mi][ni][j];
          }
}

// ---------------- launch ----------------------------------------------------
extern "C" void kernel_launch(void* const* d_in, const int* in_sizes, int n_in,
                              void* d_out, int out_size, void* d_ws, size_t ws_size,
                              hipStream_t stream) {
  const float* query = (const float*)d_in[0];
  const float* Wq = (const float*)d_in[1];
  const float* Wk = (const float*)d_in[2];
  const float* Wv = (const float*)d_in[3];
  const float* Wo = (const float*)d_in[4];
  float* out = (float*)d_out;
  char* ws = (char*)d_ws;

  // workspace carve (bytes)
  u16t* WoT     = (u16t*)(ws);                 //  2,097,152
  u16t* WqT     = (u16t*)(ws + 2097152);       //    131,072
  u16t* WkT     = (u16t*)(ws + 2228224);       //    131,072
  u16t* WvT     = (u16t*)(ws + 2359296);       //    131,072
  float* kvpart = (float*)(ws + 2490368);      // 33,554,432
  float* kspart = (float*)(ws + 36044800);     //    524,288
  u16t* kvT_g   = (u16t*)(ws + 36569088);      //    524,288
  float* ksum_g = (float*)(ws + 37093376);     //     16,384
  u16t* comb    = (u16t*)(ws + 37109760);      // 33,554,432  -> total ~70.7 MB

  la_prep<<<48, 256, 0, stream>>>(Wq, Wk, Wv, WqT, WkT, WvT);
  la_wot<<<dim3(16, 16), dim3(64, 4), 0, stream>>>(Wo, WoT);
  la_kv2<<<NBH * 32, 256, 0, stream>>>(query, WkT, WvT, kvpart, kspart);
  la_red2<<<NBH, 256, 0, stream>>>(kvpart, kspart, kvT_g, ksum_g);
  la_ctx2<<<NBH * 32, 256, 0, stream>>>(query, WqT, kvT_g, ksum_g, comb);
  la_gemm8<<<256, 512, 0, stream>>>(comb, WoT, out);
}

// Round 4
// 114.836 us; speedup vs baseline: 3.5428x; 1.0683x over previous
//
#include <hip/hip_runtime.h>
#include <stdint.h>

#define S_LEN 4096
#define NHEADS 16
#define DHEAD 64
#define EMB 1024
#define NBATCH 4
#define NBH (NBATCH * NHEADS)   // 64

typedef unsigned short u16t;
typedef __attribute__((ext_vector_type(8))) short short8;
typedef __attribute__((ext_vector_type(4))) float f32x4;

__device__ __forceinline__ u16t f2bf(float f) {
  unsigned int x = __float_as_uint(f);
  x += 0x7fffu + ((x >> 16) & 1u);
  return (u16t)(x >> 16);
}
__device__ __forceinline__ unsigned int pack2(float a, float b) {
  return (unsigned int)f2bf(a) | ((unsigned int)f2bf(b) << 16);
}
__device__ __forceinline__ float bf2f(u16t u) { return __uint_as_float(((unsigned int)u) << 16); }
__device__ __forceinline__ float phifn(float v) { return v > 0.f ? v + 1.f : __expf(v); }

// ---- stage 128x64 f32 tile (row stride EMB) -> bf16 LDS [128][72] ----------
__device__ __forceinline__ void stage_x_bf16(const float* __restrict__ xg,
                                             u16t* __restrict__ xs, int t) {
#pragma unroll
  for (int i = 0; i < 8; ++i) {
    int fi = i * 256 + t;
    int r = fi >> 4, c4 = fi & 15;
    float4 v = *(const float4*)(xg + (size_t)r * EMB + c4 * 4);
    uint2 p;
    p.x = pack2(v.x, v.y);
    p.y = pack2(v.z, v.w);
    *(uint2*)(&xs[r * 72 + c4 * 4]) = p;
  }
}

// ---- stage 8192B bf16 weight (pre-swizzled in global) via global_load_lds --
__device__ __forceinline__ void stage_w8k(const u16t* __restrict__ wg,
                                          u16t* __restrict__ lds, int t) {
#pragma unroll
  for (int c = 0; c < 2; ++c) {
    const u16t* src = wg + (size_t)(c * 256 + t) * 8;
    char* dst = (char*)lds + c * 4096 + ((t >> 6) << 10);
    __builtin_amdgcn_global_load_lds((const __attribute__((address_space(1))) unsigned int*)src,
                                     (__attribute__((address_space(3))) unsigned int*)dst,
                                     16, 0, 0);
  }
}

// ---------------- Kprep: W[h][d][e] f32 -> WT bf16 [h][e][oct^(e&7)][j] -----
__global__ __launch_bounds__(256) void la_prep(const float* __restrict__ Wq,
                                               const float* __restrict__ Wk,
                                               const float* __restrict__ Wv,
                                               u16t* __restrict__ WqT,
                                               u16t* __restrict__ WkT,
                                               u16t* __restrict__ WvT) {
  __shared__ float tmp[64][65];
  int blk = blockIdx.x;
  int mat = blk >> 4, h = blk & 15;
  const float* src = (mat == 0 ? Wq : (mat == 1 ? Wk : Wv)) + (size_t)h * 4096;
  u16t* dst = (mat == 0 ? WqT : (mat == 1 ? WkT : WvT)) + (size_t)h * 4096;
  int t = threadIdx.x;
#pragma unroll
  for (int p = 0; p < 16; ++p) {
    int i = p * 256 + t;
    tmp[i >> 6][i & 63] = src[i];
  }
  __syncthreads();
#pragma unroll
  for (int p = 0; p < 16; ++p) {
    int i = p * 256 + t;
    int e = i >> 6, r = i & 63, o = r >> 3, j = r & 7;
    dst[i] = f2bf(tmp[((o ^ (e & 7)) << 3) + j][e]);
  }
}

// ---------------- K0: transpose+cast Wo (f32 [k][n]) -> WoT (bf16 [n][k]) ----
__global__ __launch_bounds__(256) void la_wot(const float* __restrict__ Wo,
                                              u16t* __restrict__ WoT) {
  __shared__ float t[64][65];
  int n0 = blockIdx.x * 64, k0 = blockIdx.y * 64;
  int tx = threadIdx.x, ty = threadIdx.y;  // 64 x 4
  for (int r = ty; r < 64; r += 4) t[r][tx] = Wo[(size_t)(k0 + r) * EMB + n0 + tx];
  __syncthreads();
  for (int r = ty; r < 64; r += 4)
    WoT[(size_t)(n0 + r) * EMB + k0 + tx] = f2bf(t[tx][r]);
}

// ---------------- K1: q,k,v proj (MFMA) -> phiq out; kv/ksum partials -------
__global__ __launch_bounds__(256) void la_kvq3(const float* __restrict__ q,
                                               const u16t* __restrict__ WqT,
                                               const u16t* __restrict__ WkT,
                                               const u16t* __restrict__ WvT,
                                               u16t* __restrict__ phiq,
                                               float* __restrict__ kvpart,
                                               float* __restrict__ kspart) {
  __shared__ u16t xs[128 * 72];
  __shared__ u16t wq[4096];
  __shared__ u16t wk[4096];
  __shared__ u16t wv[4096];
  __shared__ u16t pkT[64 * 136];
  __shared__ u16t vT[64 * 136];
  int blk = blockIdx.x;
  int bh = blk >> 3, tile = blk & 7;
  int b = bh >> 4, h = bh & 15;
  int s0 = tile << 9;  // 512 rows per block
  int t = threadIdx.x;
  int wave = t >> 6, lane = t & 63, l16 = lane & 15, g = lane >> 4;

  stage_w8k(WqT + (size_t)h * 4096, wq, t);
  stage_w8k(WkT + (size_t)h * 4096, wk, t);
  stage_w8k(WvT + (size_t)h * 4096, wv, t);

  f32x4 kacc[4];
#pragma unroll
  for (int n = 0; n < 4; ++n) kacc[n] = 0.f;
  float ksacc = 0.f;

  for (int c = 0; c < 4; ++c) {
    if (c) __syncthreads();  // protect xs / pkT / vT from previous readers
    stage_x_bf16(q + ((size_t)b * S_LEN + s0 + c * 128) * EMB + h * 64, xs, t);
    __syncthreads();  // drains gload_lds (w-bufs on c==0) + xs visible

    f32x4 aQ[2][4], aK[2][4], aV[2][4];
#pragma unroll
    for (int m = 0; m < 2; ++m)
#pragma unroll
      for (int n = 0; n < 4; ++n) { aQ[m][n] = 0.f; aK[m][n] = 0.f; aV[m][n] = 0.f; }
    short8 af[2][2];
#pragma unroll
    for (int m = 0; m < 2; ++m)
#pragma unroll
      for (int kk = 0; kk < 2; ++kk)
        af[m][kk] = *(const short8*)(&xs[(wave * 32 + m * 16 + l16) * 72 + kk * 32 + g * 8]);
#pragma unroll
    for (int n = 0; n < 4; ++n) {
      int e = n * 16 + l16;
#pragma unroll
      for (int kk = 0; kk < 2; ++kk) {
        int op = (kk * 4 + g) ^ (l16 & 7);
        short8 bQ = *(const short8*)(&wq[e * 64 + op * 8]);
        short8 bK = *(const short8*)(&wk[e * 64 + op * 8]);
        short8 bV = *(const short8*)(&wv[e * 64 + op * 8]);
#pragma unroll
        for (int m = 0; m < 2; ++m) {
          aQ[m][n] = __builtin_amdgcn_mfma_f32_16x16x32_bf16(af[m][kk], bQ, aQ[m][n], 0, 0, 0);
          aK[m][n] = __builtin_amdgcn_mfma_f32_16x16x32_bf16(af[m][kk], bK, aK[m][n], 0, 0, 0);
          aV[m][n] = __builtin_amdgcn_mfma_f32_16x16x32_bf16(af[m][kk], bV, aV[m][n], 0, 0, 0);
        }
      }
    }
    __syncthreads();  // xs reads done -> reuse xs as phiq bounce

#pragma unroll
    for (int m = 0; m < 2; ++m)
#pragma unroll
      for (int n = 0; n < 4; ++n) {
        int e = n * 16 + l16;
#pragma unroll
        for (int j = 0; j < 4; ++j) {
          int s = wave * 32 + m * 16 + g * 4 + j;
          xs[s * 72 + e] = f2bf(phifn(aQ[m][n][j]));
          pkT[e * 136 + s] = f2bf(phifn(aK[m][n][j]));
          vT[e * 136 + s] = f2bf(aV[m][n][j]);
        }
      }
    __syncthreads();

    // coalesced phiq store (rows of 64 bf16)
#pragma unroll
    for (int i = 0; i < 4; ++i) {
      int slot = i * 256 + t;
      int r = slot >> 3, cc = (slot & 7) * 8;
      *(uint4*)(phiq + ((size_t)bh * S_LEN + s0 + c * 128 + r) * 64 + cc) =
          *(const uint4*)(&xs[r * 72 + cc]);
    }
    // kv partial accumulate (MFMA over this 128-row chunk)
#pragma unroll
    for (int ks = 0; ks < 4; ++ks) {
      short8 pa = *(const short8*)(&pkT[(wave * 16 + l16) * 136 + ks * 32 + g * 8]);
#pragma unroll
      for (int n = 0; n < 4; ++n) {
        short8 vb = *(const short8*)(&vT[(n * 16 + l16) * 136 + ks * 32 + g * 8]);
        kacc[n] = __builtin_amdgcn_mfma_f32_16x16x32_bf16(pa, vb, kacc[n], 0, 0, 0);
      }
    }
    if (t < 64) {
#pragma unroll 8
      for (int s = 0; s < 128; ++s) ksacc += bf2f(pkT[t * 136 + s]);
    }
  }

  float* kp = kvpart + (size_t)blk * 4096;
#pragma unroll
  for (int n = 0; n < 4; ++n)
#pragma unroll
    for (int j = 0; j < 4; ++j)
      kp[(wave * 16 + g * 4 + j) * 64 + n * 16 + l16] = kacc[n][j];
  if (t < 64) kspart[(size_t)blk * 64 + t] = ksacc;
}

// ---------------- K2: reduce partials; W2T[b][e][h*64+d'] = WoT_h @ kv ------
__global__ __launch_bounds__(256) void la_red3(const float* __restrict__ kvpart,
                                               const float* __restrict__ kspart,
                                               const u16t* __restrict__ WoT,
                                               float* __restrict__ ksum_g,
                                               u16t* __restrict__ W2T) {
  __shared__ float kvs[64][65];
  __shared__ u16t aT[256 * 72];
  int bh = blockIdx.x;
  int b = bh >> 4, h = bh & 15;
  int t = threadIdx.x, wave = t >> 6, lane = t & 63, l16 = lane & 15, g = lane >> 4;

  float acc[16];
#pragma unroll
  for (int i = 0; i < 16; ++i) acc[i] = 0.f;
  for (int p = 0; p < 8; ++p) {
    const float* base = kvpart + ((size_t)bh * 8 + p) * 4096;
#pragma unroll
    for (int i = 0; i < 16; ++i) acc[i] += base[i * 256 + t];
  }
#pragma unroll
  for (int i = 0; i < 16; ++i) {
    int idx = i * 256 + t;
    kvs[idx >> 6][idx & 63] = acc[i];
  }
  if (t < 64) {
    float a = 0.f;
    for (int p = 0; p < 8; ++p) a += kspart[((size_t)bh * 8 + p) * 64 + t];
    ksum_g[(size_t)bh * 64 + t] = a;
  }
  __syncthreads();

  // per-lane kv B-frags (rows d' = n*16+l16, cols kk*32+g*8..+8)
  short8 kvbf[4][2];
#pragma unroll
  for (int n = 0; n < 4; ++n)
#pragma unroll
    for (int kk = 0; kk < 2; ++kk) {
      u16t* pp = (u16t*)&kvbf[n][kk];
#pragma unroll
      for (int i = 0; i < 8; ++i) pp[i] = f2bf(kvs[n * 16 + l16][kk * 32 + g * 8 + i]);
    }

  for (int ec = 0; ec < 4; ++ec) {
    if (ec) __syncthreads();
    // stage WoT[ec*256 .. +256)[h*64 .. +64) -> aT [256][72]
#pragma unroll
    for (int p = 0; p < 8; ++p) {
      int slot = p * 256 + t;
      int r = slot >> 3, cc = (slot & 7) * 8;
      *(uint4*)(&aT[r * 72 + cc]) =
          *(const uint4*)(WoT + (size_t)(ec * 256 + r) * 1024 + h * 64 + cc);
    }
    __syncthreads();
    f32x4 c2[4][4];
#pragma unroll
    for (int mi = 0; mi < 4; ++mi)
#pragma unroll
      for (int n = 0; n < 4; ++n) c2[mi][n] = 0.f;
#pragma unroll
    for (int kk = 0; kk < 2; ++kk)
#pragma unroll
      for (int mi = 0; mi < 4; ++mi) {
        short8 afr = *(const short8*)(&aT[(wave * 64 + mi * 16 + l16) * 72 + kk * 32 + g * 8]);
#pragma unroll
        for (int n = 0; n < 4; ++n)
          c2[mi][n] = __builtin_amdgcn_mfma_f32_16x16x32_bf16(afr, kvbf[n][kk], c2[mi][n], 0, 0, 0);
      }
    __syncthreads();
#pragma unroll
    for (int mi = 0; mi < 4; ++mi)
#pragma unroll
      for (int n = 0; n < 4; ++n)
#pragma unroll
        for (int j = 0; j < 4; ++j)
          aT[(wave * 64 + mi * 16 + g * 4 + j) * 72 + n * 16 + l16] = f2bf(c2[mi][n][j]);
    __syncthreads();
#pragma unroll
    for (int p = 0; p < 8; ++p) {
      int slot = p * 256 + t;
      int r = slot >> 3, cc = (slot & 7) * 8;
      *(uint4*)(W2T + ((size_t)b << 20) + (size_t)(ec * 256 + r) * 1024 + h * 64 + cc) =
          *(const uint4*)(&aT[r * 72 + cc]);
    }
  }
}

// ---------------- K3: z = phiq . ksum; phiq2[s][h*64+d'] = phiq/(z+eps) -----
__global__ __launch_bounds__(256) void la_scale(const u16t* __restrict__ phiq,
                                                const float* __restrict__ ksum_g,
                                                u16t* __restrict__ phiq2) {
  __shared__ float ks[64];
  int blk = blockIdx.x;
  int bh = blk >> 4, sl = blk & 15;
  int b = bh >> 4, h = bh & 15;
  int s0 = sl * 256;
  int t = threadIdx.x;
  if (t < 64) ks[t] = ksum_g[(size_t)bh * 64 + t];
  __syncthreads();
  int c16 = t & 15, rg = t >> 4;
#pragma unroll 2
  for (int it = 0; it < 16; ++it) {
    int s = s0 + it * 16 + rg;
    uint2 u = *(const uint2*)(phiq + ((size_t)bh * S_LEN + s) * 64 + c16 * 4);
    float f0 = bf2f((u16t)(u.x & 0xffff)), f1 = bf2f((u16t)(u.x >> 16));
    float f2 = bf2f((u16t)(u.y & 0xffff)), f3 = bf2f((u16t)(u.y >> 16));
    float zp = f0 * ks[c16 * 4] + f1 * ks[c16 * 4 + 1] + f2 * ks[c16 * 4 + 2] + f3 * ks[c16 * 4 + 3];
    zp += __shfl_xor(zp, 1);
    zp += __shfl_xor(zp, 2);
    zp += __shfl_xor(zp, 4);
    zp += __shfl_xor(zp, 8);
    float inv = 1.f / (zp + 1e-6f);
    uint2 o;
    o.x = pack2(f0 * inv, f1 * inv);
    o.y = pack2(f2 * inv, f3 * inv);
    *(uint2*)(phiq2 + ((size_t)(b * S_LEN + s)) * EMB + h * 64 + c16 * 4) = o;
  }
}

// ---------------- K4: out = phiq2(bf16) @ W2T[b]  (256x256 8-phase) ---------
__device__ __forceinline__ void stage_half(const u16t* __restrict__ gbase,
                                           u16t* __restrict__ lbuf,
                                           int half, int t) {
#pragma unroll
  for (int it = 0; it < 2; ++it) {
    int slot = it * 512 + t;                 // 0..1023
    int row = half * 128 + (slot >> 3);      // tile row
    int oct = slot & 7;
    const u16t* src = gbase + (size_t)row * EMB + (((oct ^ (row & 7)) << 3));
    char* dst = (char*)lbuf + ((half * 128 + it * 64 + ((t >> 6) << 3)) << 7);
    __builtin_amdgcn_global_load_lds((const __attribute__((address_space(1))) unsigned int*)src,
                                     (__attribute__((address_space(3))) unsigned int*)dst,
                                     16, 0, 0);
  }
}

#define GFENCE asm volatile("" ::: "memory")

#define LOAD_A(QM)                                                              \
  _Pragma("unroll") for (int mi = 0; mi < 4; ++mi) _Pragma("unroll")            \
      for (int kk = 0; kk < 2; ++kk) {                                          \
    int rr = (QM) * 128 + wr2 * 64 + mi * 16 + l16;                             \
    afr[mi][kk] = *(const short8*)((const char*)Acur + rr * 128 +               \
                                   ((((kk << 2) | g) ^ (rr & 7)) << 4));        \
  }
#define LOAD_B(QN, DST)                                                         \
  _Pragma("unroll") for (int ni = 0; ni < 2; ++ni) _Pragma("unroll")            \
      for (int kk = 0; kk < 2; ++kk) {                                          \
    int rr = (QN) * 128 + wc2 * 32 + ni * 16 + l16;                             \
    DST[ni][kk] = *(const short8*)((const char*)Bcur + rr * 128 +               \
                                   ((((kk << 2) | g) ^ (rr & 7)) << 4));        \
  }
#define MFMA_Q(QM, QN, BF)                                                      \
  __builtin_amdgcn_s_setprio(1);                                                \
  _Pragma("unroll") for (int mi = 0; mi < 4; ++mi) _Pragma("unroll")            \
      for (int ni = 0; ni < 2; ++ni) {                                          \
    acc[QM][QN][mi][ni] = __builtin_amdgcn_mfma_f32_16x16x32_bf16(              \
        afr[mi][0], BF[ni][0], acc[QM][QN][mi][ni], 0, 0, 0);                   \
    acc[QM][QN][mi][ni] = __builtin_amdgcn_mfma_f32_16x16x32_bf16(              \
        afr[mi][1], BF[ni][1], acc[QM][QN][mi][ni], 0, 0, 0);                   \
  }                                                                             \
  __builtin_amdgcn_s_setprio(0);

#define BAR()                      \
  __builtin_amdgcn_s_barrier();    \
  GFENCE

__global__ __launch_bounds__(512, 2) void la_gemm9(const u16t* __restrict__ A,
                                                   const u16t* __restrict__ W2T,
                                                   float* __restrict__ C) {
  __shared__ u16t Al[2][16384];  // [buf][256 rows][64 cols]
  __shared__ u16t Bl[2][16384];
  int t = threadIdx.x;
  int bid = blockIdx.x;
  int swz = ((bid & 7) << 5) + (bid >> 3);  // XCD swizzle, 256 % 8 == 0
  int mt = swz >> 2, nt = swz & 3;
  const int M0 = mt * 256, N0 = nt * 256;
  const int b = mt >> 4;  // batch of this row-panel
  int wave = t >> 6, lane = t & 63;
  int l16 = lane & 15, g = lane >> 4;
  int wr2 = wave >> 2, wc2 = wave & 3;

  f32x4 acc[2][2][4][2];
#pragma unroll
  for (int qm = 0; qm < 2; ++qm)
#pragma unroll
    for (int qn = 0; qn < 2; ++qn)
#pragma unroll
      for (int mi = 0; mi < 4; ++mi)
#pragma unroll
        for (int ni = 0; ni < 2; ++ni) acc[qm][qn][mi][ni] = 0.f;

  const u16t* Asrc = A + (size_t)M0 * EMB;
  const u16t* Bsrc = W2T + ((size_t)b << 20) + (size_t)N0 * EMB;

  // prologue: tile 0 -> buf 0 (need-order), keep Bh1/Ah1 in flight
  stage_half(Asrc, Al[0], 0, t);
  stage_half(Bsrc, Bl[0], 0, t);
  stage_half(Bsrc, Bl[0], 1, t);
  stage_half(Asrc, Al[0], 1, t);
  asm volatile("s_waitcnt vmcnt(4)" ::: "memory");
  BAR();

  short8 afr[4][2], bf0[2][2], bf1[2][2];

  for (int kt = 0; kt < 15; ++kt) {
    const u16t* Acur = Al[kt & 1];
    const u16t* Bcur = Bl[kt & 1];
    u16t* Anxt = Al[(kt + 1) & 1];
    u16t* Bnxt = Bl[(kt + 1) & 1];
    const u16t* An = Asrc + (kt + 1) * 64;
    const u16t* Bn = Bsrc + (kt + 1) * 64;
    // ph0: Q00 — load A(qm0)+B(qn0); stage Ah0,Bh0
    LOAD_A(0);
    LOAD_B(0, bf0);
    stage_half(An, Anxt, 0, t);
    stage_half(Bn, Bnxt, 0, t);
    asm volatile("s_waitcnt vmcnt(6)" ::: "memory");
    BAR();
    MFMA_Q(0, 0, bf0);
    GFENCE;
    BAR();
    // ph1: Q01 — load B(qn1); stage Bh1 (A frags carried)
    LOAD_B(1, bf1);
    stage_half(Bn, Bnxt, 1, t);
    asm volatile("s_waitcnt vmcnt(6)" ::: "memory");
    BAR();
    MFMA_Q(0, 1, bf1);
    GFENCE;
    BAR();
    // ph2: Q11 — load A(qm1); stage Ah1 (B1 carried)
    LOAD_A(1);
    stage_half(An, Anxt, 1, t);
    BAR();
    MFMA_Q(1, 1, bf1);
    GFENCE;
    BAR();
    // ph3: Q10 — nothing to load (A1 + B0 carried)
    asm volatile("s_waitcnt vmcnt(4)" ::: "memory");
    BAR();
    MFMA_Q(1, 0, bf0);
    GFENCE;
    BAR();
  }
  {  // peeled last tile (kt = 15): no staging, drain
    const u16t* Acur = Al[1];
    const u16t* Bcur = Bl[1];
    LOAD_A(0);
    LOAD_B(0, bf0);
    asm volatile("s_waitcnt vmcnt(2)" ::: "memory");
    BAR();
    MFMA_Q(0, 0, bf0);
    GFENCE;
    BAR();
    LOAD_B(1, bf1);
    asm volatile("s_waitcnt vmcnt(0)" ::: "memory");
    BAR();
    MFMA_Q(0, 1, bf1);
    GFENCE;
    BAR();
    LOAD_A(1);
    BAR();
    MFMA_Q(1, 1, bf1);
    GFENCE;
    BAR();
    BAR();
    MFMA_Q(1, 0, bf0);
    GFENCE;
  }

#pragma unroll
  for (int qm = 0; qm < 2; ++qm)
#pragma unroll
    for (int qn = 0; qn < 2; ++qn)
#pragma unroll
      for (int mi = 0; mi < 4; ++mi)
#pragma unroll
        for (int ni = 0; ni < 2; ++ni)
#pragma unroll
          for (int j = 0; j < 4; ++j) {
            int row = M0 + qm * 128 + wr2 * 64 + mi * 16 + g * 4 + j;
            int col = N0 + qn * 128 + wc2 * 32 + ni * 16 + l16;
            C[(size_t)row * EMB + col] = acc[qm][qn][mi][ni][j];
          }
}

// ---------------- launch ----------------------------------------------------
extern "C" void kernel_launch(void* const* d_in, const int* in_sizes, int n_in,
                              void* d_out, int out_size, void* d_ws, size_t ws_size,
                              hipStream_t stream) {
  const float* query = (const float*)d_in[0];
  const float* Wq = (const float*)d_in[1];
  const float* Wk = (const float*)d_in[2];
  const float* Wv = (const float*)d_in[3];
  const float* Wo = (const float*)d_in[4];
  float* out = (float*)d_out;
  char* ws = (char*)d_ws;

  // workspace carve (bytes)
  u16t* WoT     = (u16t*)(ws);                 //  2,097,152
  u16t* WqT     = (u16t*)(ws + 2097152);       //    131,072
  u16t* WkT     = (u16t*)(ws + 2228224);       //    131,072
  u16t* WvT     = (u16t*)(ws + 2359296);       //    131,072
  u16t* phiq    = (u16t*)(ws + 2490368);       // 33,554,432  [bh][s][64]
  float* kvpart = (float*)(ws + 36044800);     //  8,388,608  [512][4096]
  float* kspart = (float*)(ws + 44433408);     //    131,072
  float* ksum_g = (float*)(ws + 44564480);     //     16,384
  u16t* W2T     = (u16t*)(ws + 44580864);      //  8,388,608  [b][e][k]
  u16t* phiq2   = (u16t*)(ws + 52969472);      // 33,554,432  [s][1024]
  // total ~82.5 MB

  la_prep<<<48, 256, 0, stream>>>(Wq, Wk, Wv, WqT, WkT, WvT);
  la_wot<<<dim3(16, 16), dim3(64, 4), 0, stream>>>(Wo, WoT);
  la_kvq3<<<512, 256, 0, stream>>>(query, WqT, WkT, WvT, phiq, kvpart, kspart);
  la_red3<<<NBH, 256, 0, stream>>>(kvpart, kspart, WoT, ksum_g, W2T);
  la_scale<<<1024, 256, 0, stream>>>(phiq, ksum_g, phiq2);
  la_gemm9<<<256, 512, 0, stream>>>(phiq2, W2T, out);
}